// Round 8
// baseline (236.350 us; speedup 1.0000x reference)
//
#include <hip/hip_runtime.h>

#define DIM    512
#define KCODES 8192
#define NROWS  16384
#define NEG_INF -3.402823466e38f
#define MARGIN 2.0f            // i8 pairwise err std ~0.35 -> 5.7 sigma
#define CPR 128                // cand slots per row: 32 ct * 2 windows * top-2

typedef unsigned short ushort_t;
typedef unsigned int uint_t;
typedef __attribute__((ext_vector_type(4))) int   v4i;
typedef __attribute__((ext_vector_type(4))) float v4f;

__device__ inline void dma16(const void* g, void* l) {
    __builtin_amdgcn_global_load_lds(
        (const __attribute__((address_space(1))) unsigned int*)g,
        (__attribute__((address_space(3))) unsigned int*)l, 16, 0, 0);
}

// --------- kernel 0: i8 quantize + norms + scales + k-major TRANSPOSE -------
// e_t8[sq16][8192], x_t8[sq16][16384] as int4 = 16 i8 (k-chunk of 16, row).
// Per-row scale = absmax/127. Byte LDS transpose buf[64][528].
__global__ __launch_bounds__(512) void convert_kernel(
    const float* __restrict__ x, const float* __restrict__ embed,
    int4* __restrict__ e_t8, int4* __restrict__ x_t8,
    float* __restrict__ e_sq, float* __restrict__ esqh,
    float* __restrict__ f_sq,
    float* __restrict__ e_scale, float* __restrict__ f_scale)
{
    __shared__ __align__(16) char buf[64][528];   // 33 KB

    const int w = threadIdx.x >> 6;        // 0..7
    const int lane = threadIdx.x & 63;
    const bool isE = blockIdx.x < (KCODES / 64);
    const int rows0 = isE ? blockIdx.x * 64 : (blockIdx.x - KCODES / 64) * 64;
    const float* src_base = isE ? embed : x;

    #pragma unroll
    for (int rr = 0; rr < 8; ++rr) {
        int r_local = w * 8 + rr;
        const float* src = src_base + (size_t)(rows0 + r_local) * DIM + lane * 8;
        float4 a = *(const float4*)src;
        float4 b = *(const float4*)(src + 4);
        float s = a.x*a.x + a.y*a.y + a.z*a.z + a.w*a.w
                + b.x*b.x + b.y*b.y + b.z*b.z + b.w*b.w;
        float am = fmaxf(fmaxf(fmaxf(fabsf(a.x), fabsf(a.y)), fmaxf(fabsf(a.z), fabsf(a.w))),
                         fmaxf(fmaxf(fabsf(b.x), fabsf(b.y)), fmaxf(fabsf(b.z), fabsf(b.w))));
        #pragma unroll
        for (int off = 32; off >= 1; off >>= 1) {
            s += __shfl_xor(s, off, 64);
            am = fmaxf(am, __shfl_xor(am, off, 64));
        }
        float inv = (am > 0.0f) ? 127.0f / am : 0.0f;

        float vq[8] = {a.x, a.y, a.z, a.w, b.x, b.y, b.z, b.w};
        uint_t lo = 0, hi = 0;
        #pragma unroll
        for (int jj = 0; jj < 4; ++jj) {
            lo |= ((uint_t)((int)rintf(vq[jj]     * inv) & 0xff)) << (8 * jj);
            hi |= ((uint_t)((int)rintf(vq[4 + jj] * inv) & 0xff)) << (8 * jj);
        }
        *(int*)&buf[r_local][8 * lane]     = (int)lo;
        *(int*)&buf[r_local][8 * lane + 4] = (int)hi;

        if (lane == 0) {
            int r = rows0 + r_local;
            float sc = am * (1.0f / 127.0f);
            if (isE) { e_sq[r] = s; esqh[r] = -0.5f * s; e_scale[r] = sc; }
            else     { f_sq[r] = s; f_scale[r] = sc; }
        }
    }
    __syncthreads();

    #pragma unroll
    for (int i = 0; i < 4; ++i) {
        int sq = w * 4 + i;                 // 0..31 k-chunks of 16
        int4 v = *(const int4*)&buf[lane][16 * sq];
        if (isE) e_t8[(size_t)sq * KCODES + rows0 + lane] = v;
        else     x_t8[(size_t)sq * NROWS  + rows0 + lane] = v;
    }
}

// --------- kernel 1: i8 MFMA screen — 16 waves, 64x64 wave tile -------------
// Grid: 2048 blocks = 64 row-tiles x 32 code-cols (XCD-swizzled, same map as
// before). Block tile: 256 codes x 256 rows x K=512. 16 waves as 4x4:
// wm = w&3 (64-code strip), wn = w>>2 (64-row strip). acc v4i[4][4] = 64
// regs -> __launch_bounds__(1024,4) caps 128/wave -> 4 waves/SIMD (2x the
// occupancy of every prior round; r0-r7 MfmaUtil ceiling ~44% was the
// 2-wave/SIMD latency wall from the 128-reg accumulator).
// 4 slabs of K=128, dbuf LDS 128 KB, one barrier per slab, DMA(S+1) issued
// right after it. Staging: waves 0-7 -> EH plane q=w (4 dma16), waves 8-15
// -> XH plane q=w-8 (4 dma16).
// Epilogue: per-thread top-2 over 16 codes/nj -> quad shfl merge (per-wave
// top-2 of its 64-code strip) -> LDS pair-merge of wm strips {0,1},{2,3}
// into 128-code windows (CPR unchanged; same guarantee as r7).
__global__ __launch_bounds__(1024, 4) void screen_kernel(
    const int4* __restrict__ e_t8, const int4* __restrict__ x_t8,
    const float* __restrict__ esqh,
    const float* __restrict__ e_scale, const float* __restrict__ f_scale,
    float* __restrict__ cand_s, int* __restrict__ cand_i)
{
    __shared__ __align__(16) char EH[2][8][256][16];   // 64 KB
    __shared__ __align__(16) char XH[2][8][256][16];   // 64 KB

    const int t = threadIdx.x;
    const int w = t >> 6;          // 0..15
    const int lane = t & 63;
    const int quad = lane >> 4;
    const int l15 = lane & 15;
    const int wm = w & 3;          // code strip (64)
    const int wn = w >> 2;         // row strip (64)

    const int n = blockIdx.x;
    const int xcd = n & 7;
    const int j = n >> 3;
    const int rt = xcd * 8 + (j & 7);
    const int ct = j >> 3;
    const int row0 = rt * 256;
    const int cbase = ct * 256;

    const bool isE = w < 8;
    const int qp = isE ? w : (w - 8);      // owned k16-plane
    const int4* gbase = isE ? (e_t8 + cbase + lane)
                            : (x_t8 + row0 + lane);
    const size_t gstride = isE ? KCODES : NROWS;

    v4i acc[4][4];
    #pragma unroll
    for (int mi = 0; mi < 4; ++mi)
        #pragma unroll
        for (int nj = 0; nj < 4; ++nj)
            acc[mi][nj] = (v4i){0, 0, 0, 0};

    auto issue_dma = [&](int S) {
        int buf = S & 1;
        char* ldst = isE ? &EH[buf][qp][0][0] : &XH[buf][qp][0][0];
        size_t soff = (size_t)(S * 8 + qp) * gstride;
        #pragma unroll
        for (int i = 0; i < 4; ++i)
            dma16(gbase + soff + i * 64, ldst + i * 64 * 16);
    };

    issue_dma(0);

    for (int S = 0; S < 4; ++S) {
        __syncthreads();               // drains DMA(S); DMA(S+1) overlaps compute
        if (S < 3) issue_dma(S + 1);
        const int buf = S & 1;

        #pragma unroll
        for (int ks = 0; ks < 2; ++ks) {
            const int q = ks * 4 + quad;
            v4i bh[4];
            #pragma unroll
            for (int nj = 0; nj < 4; ++nj)
                bh[nj] = *(const v4i*)(&XH[buf][q][wn * 64 + nj * 16 + l15][0]);
            #pragma unroll
            for (int mi = 0; mi < 4; ++mi) {
                v4i ah = *(const v4i*)(&EH[buf][q][wm * 64 + mi * 16 + l15][0]);
                #pragma unroll
                for (int nj = 0; nj < 4; ++nj)
                    acc[mi][nj] = __builtin_amdgcn_mfma_i32_16x16x64_i8(ah, bh[nj], acc[mi][nj], 0, 0, 0);
            }
        }
    }

    // ---- epilogue: per-code scores -> per-strip top-2 -> pair-merge --------
    __syncthreads();                       // main-loop LDS reads done; reuse as scratch
    float* scr_s = (float*)&EH[0][0][0][0];    // [4 wm][256 row][2]  (8 KB)
    int*   scr_i = (int*)  &XH[0][0][0][0];    // [4 wm][256 row][2]  (8 KB)

    #pragma unroll
    for (int nj = 0; nj < 4; ++nj) {
        float sfv = f_scale[row0 + wn * 64 + nj * 16 + l15];
        float b1 = NEG_INF, b2 = NEG_INF;
        int   i1 = 0x7fffffff, i2 = 0x7fffffff;
        #pragma unroll
        for (int mi = 0; mi < 4; ++mi) {
            v4f se4 = *(const v4f*)(e_scale + cbase + wm * 64 + mi * 16 + quad * 4);
            v4f eq4 = *(const v4f*)(esqh    + cbase + wm * 64 + mi * 16 + quad * 4);
            int cid0 = cbase + wm * 64 + mi * 16 + quad * 4;
            #pragma unroll
            for (int jj = 0; jj < 4; ++jj) {
                float sc = fmaf(sfv * se4[jj], (float)acc[mi][nj][jj], eq4[jj]);
                int cc = cid0 + jj;
                if (sc > b1)      { b2 = b1; i2 = i1; b1 = sc; i1 = cc; }
                else if (sc > b2) { b2 = sc; i2 = cc; }
            }
        }
        #pragma unroll
        for (int o = 16; o <= 32; o <<= 1) {   // merge across the 4 quads
            float c1 = __shfl_xor(b1, o, 64);
            int   j1 = __shfl_xor(i1, o, 64);
            float c2 = __shfl_xor(b2, o, 64);
            int   j2 = __shfl_xor(i2, o, 64);
            if (c1 > b1) {
                b2 = fmaxf(b1, c2); i2 = (b1 >= c2) ? i1 : j2;
                b1 = c1; i1 = j1;
            } else {
                i2 = (b2 >= c1) ? i2 : j1;
                b2 = fmaxf(b2, c1);
            }
        }
        if (quad == 0) {
            int rl = wn * 64 + nj * 16 + l15;       // block-local row 0..255
            int base = (wm * 256 + rl) * 2;
            scr_s[base]     = b1;  scr_i[base]     = i1;
            scr_s[base + 1] = b2;  scr_i[base + 1] = i2;
        }
    }
    __syncthreads();

    if (t < 512) {
        int rl = t >> 1;                   // block-local row
        int pr = t & 1;                    // window: wm strips {0,1} or {2,3}
        int ba = ((2 * pr) * 256 + rl) * 2;
        int bb = ((2 * pr + 1) * 256 + rl) * 2;
        float a1 = scr_s[ba], a2 = scr_s[ba + 1];
        int   ia = scr_i[ba], i2a = scr_i[ba + 1];
        float c1 = scr_s[bb], c2 = scr_s[bb + 1];
        int   ic = scr_i[bb], i2c = scr_i[bb + 1];
        float b1, b2; int j1, j2;
        if (a1 >= c1) {
            b1 = a1; j1 = ia;
            if (a2 >= c1) { b2 = a2; j2 = i2a; } else { b2 = c1; j2 = ic; }
        } else {
            b1 = c1; j1 = ic;
            if (c2 >= a1) { b2 = c2; j2 = i2c; } else { b2 = a1; j2 = ia; }
        }
        size_t b = (size_t)(row0 + rl) * CPR + (ct * 4 + pr * 2);
        cand_s[b]     = b1;  cand_i[b]     = j1;
        cand_s[b + 1] = b2;  cand_i[b + 1] = j2;
    }
}

// --------- kernel 2: exact fp32 rescore of surviving CODES + gather ---------
__global__ __launch_bounds__(256) void rescore_kernel(
    const float* __restrict__ x, const float* __restrict__ embed,
    const float* __restrict__ e_sq, const float* __restrict__ f_sq,
    const float* __restrict__ cand_s, const int* __restrict__ cand_i,
    float* __restrict__ out)
{
    int row = blockIdx.x * 4 + (threadIdx.x >> 6);
    int lane = threadIdx.x & 63;
    size_t cb = (size_t)row * CPR;

    float cs0 = cand_s[cb + lane];
    float cs1 = cand_s[cb + 64 + lane];
    int   ci0 = cand_i[cb + lane];
    int   ci1 = cand_i[cb + 64 + lane];

    float m = fmaxf(cs0, cs1);
    #pragma unroll
    for (int o = 32; o >= 1; o >>= 1) m = fmaxf(m, __shfl_xor(m, o, 64));

    unsigned long long mask0 = __ballot(cs0 >= m - MARGIN);
    unsigned long long mask1 = __ballot(cs1 >= m - MARGIN);

    const float4* xsrc = (const float4*)(x + (size_t)row * DIM + lane * 8);
    float4 xa = xsrc[0], xb = xsrc[1];
    float fsq = f_sq[row];

    float bd = NEG_INF;
    int   bi = 0x7fffffff;

    #pragma unroll
    for (int s = 0; s < 2; ++s) {
        unsigned long long mask = s ? mask1 : mask0;
        while (mask) {
            int p = __ffsll(mask) - 1;
            mask &= mask - 1;
            int c = __shfl(s ? ci1 : ci0, p);
            const float4* er = (const float4*)(embed + (size_t)c * DIM + lane * 8);
            float4 ea = er[0], eb = er[1];
            float part = xa.x*ea.x + xa.y*ea.y + xa.z*ea.z + xa.w*ea.w
                       + xb.x*eb.x + xb.y*eb.y + xb.z*eb.z + xb.w*eb.w;
            #pragma unroll
            for (int o = 32; o >= 1; o >>= 1) part += __shfl_xor(part, o, 64);
            float d = -((fsq - 2.0f * part) + e_sq[c]);   // np rounding order
            if (d > bd || (d == bd && c < bi)) { bd = d; bi = c; }
        }
    }

    const float4* er = (const float4*)(embed + (size_t)bi * DIM + lane * 8);
    float4 qa = er[0], qb = er[1];
    float4* dst = (float4*)(out + (size_t)row * DIM + lane * 8);
    dst[0] = qa; dst[1] = qb;
    if (lane == 0) out[(size_t)NROWS * DIM + row] = (float)bi;
}

extern "C" void kernel_launch(void* const* d_in, const int* in_sizes, int n_in,
                              void* d_out, int out_size, void* d_ws, size_t ws_size,
                              hipStream_t stream)
{
    const float* x     = (const float*)d_in[0];   // [16384, 512] fp32
    const float* embed = (const float*)d_in[1];   // [8192, 512] fp32
    float* out = (float*)d_out;

    // ws layout (~21 MB), all 16B-aligned
    float* e_sq    = (float*)d_ws;                              // 8192
    float* esqh    = e_sq + KCODES;                             // 8192 (-e_sq/2)
    float* f_sq    = esqh + KCODES;                             // 16384
    float* e_scale = f_sq + NROWS;                              // 8192
    float* f_scale = e_scale + KCODES;                          // 16384
    float* cand_s  = f_scale + NROWS;                           // 16384*128
    int*   cand_i  = (int*)(cand_s + (size_t)NROWS * CPR);      // 16384*128
    int4*  e_t8    = (int4*)(cand_i + (size_t)NROWS * CPR);     // [32][8192] int4 = 4 MB

    // x_t8 lives in d_out scratch (8 MB of 33.6 MB); rescore overwrites later.
    int4* x_t8 = (int4*)d_out;

    (void)in_sizes; (void)n_in; (void)out_size; (void)ws_size;

    convert_kernel<<<(KCODES + NROWS) / 64, 512, 0, stream>>>(
        x, embed, e_t8, x_t8, e_sq, esqh, f_sq, e_scale, f_scale);
    screen_kernel<<<2048, 1024, 0, stream>>>(
        e_t8, x_t8, esqh, e_scale, f_scale, cand_s, cand_i);
    rescore_kernel<<<NROWS / 4, 256, 0, stream>>>(
        x, embed, e_sq, f_sq, cand_s, cand_i, out);
}

// Round 9
// 229.401 us; speedup vs baseline: 1.0303x; 1.0303x over previous
//
#include <hip/hip_runtime.h>

#define DIM    512
#define KCODES 8192
#define NROWS  16384
#define NEG_INF -3.402823466e38f
#define MARGIN 2.0f            // i8 pairwise err std ~0.35 -> 5.7 sigma
#define CPR 128                // cand slots per row: 64 ct windows * top-2

typedef unsigned short ushort_t;
typedef unsigned int uint_t;
typedef __attribute__((ext_vector_type(4))) int   v4i;
typedef __attribute__((ext_vector_type(4))) float v4f;

__device__ inline void dma16(const void* g, void* l) {
    __builtin_amdgcn_global_load_lds(
        (const __attribute__((address_space(1))) unsigned int*)g,
        (__attribute__((address_space(3))) unsigned int*)l, 16, 0, 0);
}

// --------- kernel 0: i8 quantize + norms + scales + k-major TRANSPOSE -------
// e_t8[sq16][8192], x_t8[sq16][16384] as int4 = 16 i8 (k-chunk of 16, row).
// Per-row scale = absmax/127. Byte LDS transpose buf[64][528].
__global__ __launch_bounds__(512) void convert_kernel(
    const float* __restrict__ x, const float* __restrict__ embed,
    int4* __restrict__ e_t8, int4* __restrict__ x_t8,
    float* __restrict__ e_sq, float* __restrict__ esqh,
    float* __restrict__ f_sq,
    float* __restrict__ e_scale, float* __restrict__ f_scale)
{
    __shared__ __align__(16) char buf[64][528];   // 33 KB

    const int w = threadIdx.x >> 6;        // 0..7
    const int lane = threadIdx.x & 63;
    const bool isE = blockIdx.x < (KCODES / 64);
    const int rows0 = isE ? blockIdx.x * 64 : (blockIdx.x - KCODES / 64) * 64;
    const float* src_base = isE ? embed : x;

    #pragma unroll
    for (int rr = 0; rr < 8; ++rr) {
        int r_local = w * 8 + rr;
        const float* src = src_base + (size_t)(rows0 + r_local) * DIM + lane * 8;
        float4 a = *(const float4*)src;
        float4 b = *(const float4*)(src + 4);
        float s = a.x*a.x + a.y*a.y + a.z*a.z + a.w*a.w
                + b.x*b.x + b.y*b.y + b.z*b.z + b.w*b.w;
        float am = fmaxf(fmaxf(fmaxf(fabsf(a.x), fabsf(a.y)), fmaxf(fabsf(a.z), fabsf(a.w))),
                         fmaxf(fmaxf(fabsf(b.x), fabsf(b.y)), fmaxf(fabsf(b.z), fabsf(b.w))));
        #pragma unroll
        for (int off = 32; off >= 1; off >>= 1) {
            s += __shfl_xor(s, off, 64);
            am = fmaxf(am, __shfl_xor(am, off, 64));
        }
        float inv = (am > 0.0f) ? 127.0f / am : 0.0f;

        float vq[8] = {a.x, a.y, a.z, a.w, b.x, b.y, b.z, b.w};
        uint_t lo = 0, hi = 0;
        #pragma unroll
        for (int jj = 0; jj < 4; ++jj) {
            lo |= ((uint_t)((int)rintf(vq[jj]     * inv) & 0xff)) << (8 * jj);
            hi |= ((uint_t)((int)rintf(vq[4 + jj] * inv) & 0xff)) << (8 * jj);
        }
        *(int*)&buf[r_local][8 * lane]     = (int)lo;
        *(int*)&buf[r_local][8 * lane + 4] = (int)hi;

        if (lane == 0) {
            int r = rows0 + r_local;
            float sc = am * (1.0f / 127.0f);
            if (isE) { e_sq[r] = s; esqh[r] = -0.5f * s; e_scale[r] = sc; }
            else     { f_sq[r] = s; f_scale[r] = sc; }
        }
    }
    __syncthreads();

    #pragma unroll
    for (int i = 0; i < 4; ++i) {
        int sq = w * 4 + i;                 // 0..31 k-chunks of 16
        int4 v = *(const int4*)&buf[lane][16 * sq];
        if (isE) e_t8[(size_t)sq * KCODES + rows0 + lane] = v;
        else     x_t8[(size_t)sq * NROWS  + rows0 + lane] = v;
    }
}

// --------- kernel 1: i8 MFMA screen — 256-thr blocks, 3 blocks/CU -----------
// r0-r8 lesson: matrix pipe always runs at its floor (MfmaUtil*dur ~= i8
// floor); duration is set by barrier/DMA wait that LOCKSTEP blocks cannot
// hide. Occupancy math: waves/SIMD * regs <= 512. 1024-thr block -> <=128
// regs (r8: spilled). 256-thr blocks at 3 blocks/CU -> <=170 regs: fits
// acc 64 + ~100 arch with headroom, and the 3 co-resident blocks are
// barrier-INDEPENDENT (m114 overlap: one block's MFMA covers another's
// DMA drain).
// Grid: 8192 = 128 rt x 64 ct. Swizzle: each XCD owns an 8-ct stripe
// (E stripe 512 KB -> L2-resident; X tile reused x8 consecutively).
// Block tile: 128 codes x 128 rows x K=512; wave tile 64x64 (acc v4i[4][4]
// = 64 regs). 8 slabs of K=64 (4 k16-planes), dbuf LDS 32 KB/block, one
// barrier per slab, DMA(S+1) right after. Wave w stages plane w (4 dma16).
// Epilogue: per-thread top-2 of 16 codes/nj -> quad shfl merge (per-wave
// top-2 of 64-strip) -> LDS pair-merge of the 2 wm strips -> per-row top-2
// of this block's 128-code window. CPR slots [2ct, 2ct+1]; same guarantee
// and MARGIN as r7 (absmax 0 proven).
__global__ __launch_bounds__(256, 3) void screen_kernel(
    const int4* __restrict__ e_t8, const int4* __restrict__ x_t8,
    const float* __restrict__ esqh,
    const float* __restrict__ e_scale, const float* __restrict__ f_scale,
    float* __restrict__ cand_s, int* __restrict__ cand_i)
{
    __shared__ __align__(16) char EH[2][4][128][16];   // 16 KB
    __shared__ __align__(16) char XH[2][4][128][16];   // 16 KB

    const int t = threadIdx.x;
    const int w = t >> 6;          // 0..3
    const int lane = t & 63;
    const int quad = lane >> 4;
    const int l15 = lane & 15;
    const int wm = w & 1;          // code strip (64)
    const int wn = w >> 1;         // row strip (64)

    const int n = blockIdx.x;
    const int xcd = n & 7;
    const int m = n >> 3;
    const int ct = xcd * 8 + (m & 7);      // 0..63 (8-ct stripe per XCD)
    const int rt = m >> 3;                 // 0..127
    const int row0 = rt * 128;
    const int cbase = ct * 128;

    const int4* ep = e_t8 + cbase + lane;
    const int4* xp = x_t8 + row0 + lane;

    v4i acc[4][4];
    #pragma unroll
    for (int mi = 0; mi < 4; ++mi)
        #pragma unroll
        for (int nj = 0; nj < 4; ++nj)
            acc[mi][nj] = (v4i){0, 0, 0, 0};

    auto issue_dma = [&](int S) {
        int buf = S & 1;
        size_t sq = (size_t)(S * 4 + w);       // k16-plane 0..31, wave owns p=w
        dma16(ep + sq * KCODES,      &EH[buf][w][0][0]);
        dma16(ep + sq * KCODES + 64, &EH[buf][w][64][0]);
        dma16(xp + sq * NROWS,       &XH[buf][w][0][0]);
        dma16(xp + sq * NROWS + 64,  &XH[buf][w][64][0]);
    };

    issue_dma(0);

    for (int S = 0; S < 8; ++S) {
        __syncthreads();               // drains DMA(S); DMA(S+1) overlaps compute
        if (S < 7) issue_dma(S + 1);
        const int buf = S & 1;

        v4i bh[4];
        #pragma unroll
        for (int nj = 0; nj < 4; ++nj)
            bh[nj] = *(const v4i*)(&XH[buf][quad][wn * 64 + nj * 16 + l15][0]);
        __builtin_amdgcn_s_setprio(1);
        #pragma unroll
        for (int mi = 0; mi < 4; ++mi) {
            v4i ah = *(const v4i*)(&EH[buf][quad][wm * 64 + mi * 16 + l15][0]);
            #pragma unroll
            for (int nj = 0; nj < 4; ++nj)
                acc[mi][nj] = __builtin_amdgcn_mfma_i32_16x16x64_i8(ah, bh[nj], acc[mi][nj], 0, 0, 0);
        }
        __builtin_amdgcn_s_setprio(0);
    }

    // ---- epilogue: per-code scores -> per-strip top-2 -> pair-merge --------
    __syncthreads();                       // main-loop LDS reads done; reuse as scratch
    float* scr_s = (float*)&EH[0][0][0][0];    // [2 wm][128 row][2]  (2 KB)
    int*   scr_i = (int*)  &XH[0][0][0][0];    // [2 wm][128 row][2]  (2 KB)

    #pragma unroll
    for (int nj = 0; nj < 4; ++nj) {
        float sfv = f_scale[row0 + wn * 64 + nj * 16 + l15];
        float b1 = NEG_INF, b2 = NEG_INF;
        int   i1 = 0x7fffffff, i2 = 0x7fffffff;
        #pragma unroll
        for (int mi = 0; mi < 4; ++mi) {
            v4f se4 = *(const v4f*)(e_scale + cbase + wm * 64 + mi * 16 + quad * 4);
            v4f eq4 = *(const v4f*)(esqh    + cbase + wm * 64 + mi * 16 + quad * 4);
            int cid0 = cbase + wm * 64 + mi * 16 + quad * 4;
            #pragma unroll
            for (int jj = 0; jj < 4; ++jj) {
                float sc = fmaf(sfv * se4[jj], (float)acc[mi][nj][jj], eq4[jj]);
                int cc = cid0 + jj;
                if (sc > b1)      { b2 = b1; i2 = i1; b1 = sc; i1 = cc; }
                else if (sc > b2) { b2 = sc; i2 = cc; }
            }
        }
        #pragma unroll
        for (int o = 16; o <= 32; o <<= 1) {   // merge across the 4 quads
            float c1 = __shfl_xor(b1, o, 64);
            int   j1 = __shfl_xor(i1, o, 64);
            float c2 = __shfl_xor(b2, o, 64);
            int   j2 = __shfl_xor(i2, o, 64);
            if (c1 > b1) {
                b2 = fmaxf(b1, c2); i2 = (b1 >= c2) ? i1 : j2;
                b1 = c1; i1 = j1;
            } else {
                i2 = (b2 >= c1) ? i2 : j1;
                b2 = fmaxf(b2, c1);
            }
        }
        if (quad == 0) {
            int rl = wn * 64 + nj * 16 + l15;       // block-local row 0..127
            int base = (wm * 128 + rl) * 2;
            scr_s[base]     = b1;  scr_i[base]     = i1;
            scr_s[base + 1] = b2;  scr_i[base + 1] = i2;
        }
    }
    __syncthreads();

    if (t < 128) {
        int rl = t;                        // block-local row
        int ba = rl * 2;
        int bb = (128 + rl) * 2;
        float a1 = scr_s[ba], a2 = scr_s[ba + 1];
        int   ia = scr_i[ba], i2a = scr_i[ba + 1];
        float c1 = scr_s[bb], c2 = scr_s[bb + 1];
        int   ic = scr_i[bb], i2c = scr_i[bb + 1];
        float b1, b2; int j1, j2;
        if (a1 >= c1) {
            b1 = a1; j1 = ia;
            if (a2 >= c1) { b2 = a2; j2 = i2a; } else { b2 = c1; j2 = ic; }
        } else {
            b1 = c1; j1 = ic;
            if (c2 >= a1) { b2 = c2; j2 = i2c; } else { b2 = a1; j2 = ia; }
        }
        size_t b = (size_t)(row0 + rl) * CPR + (size_t)(ct * 2);
        cand_s[b]     = b1;  cand_i[b]     = j1;
        cand_s[b + 1] = b2;  cand_i[b + 1] = j2;
    }
}

// --------- kernel 2: exact fp32 rescore of surviving CODES + gather ---------
__global__ __launch_bounds__(256) void rescore_kernel(
    const float* __restrict__ x, const float* __restrict__ embed,
    const float* __restrict__ e_sq, const float* __restrict__ f_sq,
    const float* __restrict__ cand_s, const int* __restrict__ cand_i,
    float* __restrict__ out)
{
    int row = blockIdx.x * 4 + (threadIdx.x >> 6);
    int lane = threadIdx.x & 63;
    size_t cb = (size_t)row * CPR;

    float cs0 = cand_s[cb + lane];
    float cs1 = cand_s[cb + 64 + lane];
    int   ci0 = cand_i[cb + lane];
    int   ci1 = cand_i[cb + 64 + lane];

    float m = fmaxf(cs0, cs1);
    #pragma unroll
    for (int o = 32; o >= 1; o >>= 1) m = fmaxf(m, __shfl_xor(m, o, 64));

    unsigned long long mask0 = __ballot(cs0 >= m - MARGIN);
    unsigned long long mask1 = __ballot(cs1 >= m - MARGIN);

    const float4* xsrc = (const float4*)(x + (size_t)row * DIM + lane * 8);
    float4 xa = xsrc[0], xb = xsrc[1];
    float fsq = f_sq[row];

    float bd = NEG_INF;
    int   bi = 0x7fffffff;

    #pragma unroll
    for (int s = 0; s < 2; ++s) {
        unsigned long long mask = s ? mask1 : mask0;
        while (mask) {
            int p = __ffsll(mask) - 1;
            mask &= mask - 1;
            int c = __shfl(s ? ci1 : ci0, p);
            const float4* er = (const float4*)(embed + (size_t)c * DIM + lane * 8);
            float4 ea = er[0], eb = er[1];
            float part = xa.x*ea.x + xa.y*ea.y + xa.z*ea.z + xa.w*ea.w
                       + xb.x*eb.x + xb.y*eb.y + xb.z*eb.z + xb.w*eb.w;
            #pragma unroll
            for (int o = 32; o >= 1; o >>= 1) part += __shfl_xor(part, o, 64);
            float d = -((fsq - 2.0f * part) + e_sq[c]);   // np rounding order
            if (d > bd || (d == bd && c < bi)) { bd = d; bi = c; }
        }
    }

    const float4* er = (const float4*)(embed + (size_t)bi * DIM + lane * 8);
    float4 qa = er[0], qb = er[1];
    float4* dst = (float4*)(out + (size_t)row * DIM + lane * 8);
    dst[0] = qa; dst[1] = qb;
    if (lane == 0) out[(size_t)NROWS * DIM + row] = (float)bi;
}

extern "C" void kernel_launch(void* const* d_in, const int* in_sizes, int n_in,
                              void* d_out, int out_size, void* d_ws, size_t ws_size,
                              hipStream_t stream)
{
    const float* x     = (const float*)d_in[0];   // [16384, 512] fp32
    const float* embed = (const float*)d_in[1];   // [8192, 512] fp32
    float* out = (float*)d_out;

    // ws layout (~21 MB), all 16B-aligned
    float* e_sq    = (float*)d_ws;                              // 8192
    float* esqh    = e_sq + KCODES;                             // 8192 (-e_sq/2)
    float* f_sq    = esqh + KCODES;                             // 16384
    float* e_scale = f_sq + NROWS;                              // 8192
    float* f_scale = e_scale + KCODES;                          // 16384
    float* cand_s  = f_scale + NROWS;                           // 16384*128
    int*   cand_i  = (int*)(cand_s + (size_t)NROWS * CPR);      // 16384*128
    int4*  e_t8    = (int4*)(cand_i + (size_t)NROWS * CPR);     // [32][8192] int4 = 4 MB

    // x_t8 lives in d_out scratch (8 MB of 33.6 MB); rescore overwrites later.
    int4* x_t8 = (int4*)d_out;

    (void)in_sizes; (void)n_in; (void)out_size; (void)ws_size;

    convert_kernel<<<(KCODES + NROWS) / 64, 512, 0, stream>>>(
        x, embed, e_t8, x_t8, e_sq, esqh, f_sq, e_scale, f_scale);
    screen_kernel<<<8192, 256, 0, stream>>>(
        e_t8, x_t8, esqh, e_scale, f_scale, cand_s, cand_i);
    rescore_kernel<<<NROWS / 4, 256, 0, stream>>>(
        x, embed, e_sq, f_sq, cand_s, cand_i, out);
}

// Round 10
// 224.585 us; speedup vs baseline: 1.0524x; 1.0214x over previous
//
#include <hip/hip_runtime.h>

#define DIM    512
#define KCODES 8192
#define NROWS  16384
#define NEG_INF -3.402823466e38f
#define MARGIN 2.0f            // i8 pairwise err std ~0.35 -> 5.7 sigma
#define CPR 128                // cand slots per row: 32 ct * 2 wm * top-2

typedef unsigned short ushort_t;
typedef unsigned int uint_t;
typedef __attribute__((ext_vector_type(4))) int   v4i;
typedef __attribute__((ext_vector_type(4))) float v4f;

__device__ inline void dma16(const void* g, void* l) {
    __builtin_amdgcn_global_load_lds(
        (const __attribute__((address_space(1))) unsigned int*)g,
        (__attribute__((address_space(3))) unsigned int*)l, 16, 0, 0);
}

// --------- kernel 0: i8 quantize + norms + scales + k-major TRANSPOSE -------
// 32-row tiles, 768 blocks x 512 thr (3 blocks/CU): halves the per-thread
// serial chain vs r9 and triples machine parallelism. Per-row math order
// identical (full 64-lane rows, same shfl tree) => bit-identical outputs.
__global__ __launch_bounds__(512) void convert_kernel(
    const float* __restrict__ x, const float* __restrict__ embed,
    int4* __restrict__ e_t8, int4* __restrict__ x_t8,
    float* __restrict__ e_sq, float* __restrict__ esqh,
    float* __restrict__ f_sq,
    float* __restrict__ e_scale, float* __restrict__ f_scale)
{
    __shared__ __align__(16) char buf[32][528];   // 16.5 KB

    const int w = threadIdx.x >> 6;        // 0..7
    const int lane = threadIdx.x & 63;
    const bool isE = blockIdx.x < (KCODES / 32);
    const int rows0 = isE ? blockIdx.x * 32 : (blockIdx.x - KCODES / 32) * 32;
    const float* src_base = isE ? embed : x;

    #pragma unroll
    for (int rr = 0; rr < 4; ++rr) {
        int r_local = w * 4 + rr;
        const float* src = src_base + (size_t)(rows0 + r_local) * DIM + lane * 8;
        float4 a = *(const float4*)src;
        float4 b = *(const float4*)(src + 4);
        float s = a.x*a.x + a.y*a.y + a.z*a.z + a.w*a.w
                + b.x*b.x + b.y*b.y + b.z*b.z + b.w*b.w;
        float am = fmaxf(fmaxf(fmaxf(fabsf(a.x), fabsf(a.y)), fmaxf(fabsf(a.z), fabsf(a.w))),
                         fmaxf(fmaxf(fabsf(b.x), fabsf(b.y)), fmaxf(fabsf(b.z), fabsf(b.w))));
        #pragma unroll
        for (int off = 32; off >= 1; off >>= 1) {
            s += __shfl_xor(s, off, 64);
            am = fmaxf(am, __shfl_xor(am, off, 64));
        }
        float inv = (am > 0.0f) ? 127.0f / am : 0.0f;

        float vq[8] = {a.x, a.y, a.z, a.w, b.x, b.y, b.z, b.w};
        uint_t lo = 0, hi = 0;
        #pragma unroll
        for (int jj = 0; jj < 4; ++jj) {
            lo |= ((uint_t)((int)rintf(vq[jj]     * inv) & 0xff)) << (8 * jj);
            hi |= ((uint_t)((int)rintf(vq[4 + jj] * inv) & 0xff)) << (8 * jj);
        }
        *(int*)&buf[r_local][8 * lane]     = (int)lo;
        *(int*)&buf[r_local][8 * lane + 4] = (int)hi;

        if (lane == 0) {
            int r = rows0 + r_local;
            float sc = am * (1.0f / 127.0f);
            if (isE) { e_sq[r] = s; esqh[r] = -0.5f * s; e_scale[r] = sc; }
            else     { f_sq[r] = s; f_scale[r] = sc; }
        }
    }
    __syncthreads();

    const int t = threadIdx.x;
    #pragma unroll
    for (int i = 0; i < 2; ++i) {
        int idx = t + i * 512;             // 0..1023 = (sq 0..31) x (row 0..31)
        int sq  = idx >> 5;
        int row = idx & 31;
        int4 v = *(const int4*)&buf[row][16 * sq];
        if (isE) e_t8[(size_t)sq * KCODES + rows0 + row] = v;
        else     x_t8[(size_t)sq * NROWS  + rows0 + row] = v;
    }
}

// --------- kernel 1: i8 MFMA screen — r7 base + pipelined epilogue scales ---
// Grid: 2048 blocks = 64 row-tiles x 32 code-cols (XCD-swizzled). 1 block/CU.
// Block tile: 256 codes x 256 rows x K=512; wave tile 128x64 (lowest
// (M+N)/(M*N) read floor of all tried configs), acc v4i[8][4] = 128 regs
// (2 waves/SIMD). 4 slabs of K=128, dbuf LDS 128 KB, one barrier per slab,
// DMA(S+1) right after it. Main loop verbatim from r7 (proven, absmax 0).
// Epilogue: mi-outer / nj-inner with 2-deep software pipeline on se4/eq4
// (r6->r7 regression isolated to these loads: 32 chained in-loop loads cost
// ~30us exposed latency; preloading all 64 regs spilled in r6). Per-nj
// insert order (mi asc, jj asc) identical to r7 => bit-identical candidates.
__global__ __launch_bounds__(512, 2) void screen_kernel(
    const int4* __restrict__ e_t8, const int4* __restrict__ x_t8,
    const float* __restrict__ esqh,
    const float* __restrict__ e_scale, const float* __restrict__ f_scale,
    float* __restrict__ cand_s, int* __restrict__ cand_i)
{
    __shared__ __align__(16) char EH[2][8][256][16];   // 64 KB
    __shared__ __align__(16) char XH[2][8][256][16];   // 64 KB

    const int t = threadIdx.x;
    const int w = t >> 6;          // 0..7
    const int lane = t & 63;
    const int quad = lane >> 4;
    const int l15 = lane & 15;
    const int wm = w & 1;          // code half (128)
    const int wn = w >> 1;         // row quarter (64)

    const int n = blockIdx.x;
    const int xcd = n & 7;
    const int j = n >> 3;
    const int rt = xcd * 8 + (j & 7);
    const int ct = j >> 3;
    const int row0 = rt * 256;
    const int cbase = ct * 256;

    const bool isE = w < 4;
    const int4* gbase = isE ? (e_t8 + cbase + w * 64 + lane)
                            : (x_t8 + row0 + (w - 4) * 64 + lane);
    const size_t gstride = isE ? KCODES : NROWS;

    v4i acc[8][4];
    #pragma unroll
    for (int mi = 0; mi < 8; ++mi)
        #pragma unroll
        for (int nj = 0; nj < 4; ++nj)
            acc[mi][nj] = (v4i){0, 0, 0, 0};

    auto issue_dma = [&](int S) {
        int buf = S & 1;
        char* ldst = isE ? &EH[buf][0][(w & 3) * 64][0] : &XH[buf][0][(w & 3) * 64][0];
        #pragma unroll
        for (int q = 0; q < 8; ++q) {
            int sq = S * 8 + q;                    // global k16-plane 0..31
            dma16(gbase + (size_t)sq * gstride, ldst + q * 256 * 16);
        }
    };

    issue_dma(0);

    for (int S = 0; S < 4; ++S) {
        __syncthreads();               // drains DMA(S); DMA(S+1) overlaps compute
        if (S < 3) issue_dma(S + 1);
        const int buf = S & 1;

        #pragma unroll
        for (int ks = 0; ks < 2; ++ks) {
            const int q = ks * 4 + quad;
            v4i bh[4];
            #pragma unroll
            for (int nj = 0; nj < 4; ++nj)
                bh[nj] = *(const v4i*)(&XH[buf][q][wn * 64 + nj * 16 + l15][0]);
            #pragma unroll
            for (int mi = 0; mi < 8; ++mi) {
                v4i ah = *(const v4i*)(&EH[buf][q][wm * 128 + mi * 16 + l15][0]);
                #pragma unroll
                for (int nj = 0; nj < 4; ++nj)
                    acc[mi][nj] = __builtin_amdgcn_mfma_i32_16x16x64_i8(ah, bh[nj], acc[mi][nj], 0, 0, 0);
            }
        }
    }

    // ---- epilogue: per-code scores -> top-2 per 128-window (pipelined) -----
    float sfv[4];
    #pragma unroll
    for (int nj = 0; nj < 4; ++nj)
        sfv[nj] = f_scale[row0 + wn * 64 + nj * 16 + l15];

    float b1[4], b2[4];
    int   i1[4], i2[4];
    #pragma unroll
    for (int nj = 0; nj < 4; ++nj) {
        b1[nj] = NEG_INF; b2[nj] = NEG_INF;
        i1[nj] = 0x7fffffff; i2[nj] = 0x7fffffff;
    }

    const float* se_base = e_scale + cbase + wm * 128 + quad * 4;
    const float* eq_base = esqh    + cbase + wm * 128 + quad * 4;

    v4f seC = *(const v4f*)(se_base);
    v4f eqC = *(const v4f*)(eq_base);
    #pragma unroll
    for (int mi = 0; mi < 8; ++mi) {
        v4f seN, eqN;
        if (mi < 7) {                       // prefetch next mi's scales
            seN = *(const v4f*)(se_base + (mi + 1) * 16);
            eqN = *(const v4f*)(eq_base + (mi + 1) * 16);
        }
        int cid0 = cbase + wm * 128 + mi * 16 + quad * 4;
        #pragma unroll
        for (int nj = 0; nj < 4; ++nj) {
            #pragma unroll
            for (int jj = 0; jj < 4; ++jj) {
                float sc = fmaf(sfv[nj] * seC[jj], (float)acc[mi][nj][jj], eqC[jj]);
                int cc = cid0 + jj;
                if (sc > b1[nj])      { b2[nj] = b1[nj]; i2[nj] = i1[nj]; b1[nj] = sc; i1[nj] = cc; }
                else if (sc > b2[nj]) { b2[nj] = sc; i2[nj] = cc; }
            }
        }
        seC = seN; eqC = eqN;
    }

    #pragma unroll
    for (int nj = 0; nj < 4; ++nj) {
        float a1 = b1[nj], a2 = b2[nj];
        int   x1 = i1[nj], x2 = i2[nj];
        #pragma unroll
        for (int o = 16; o <= 32; o <<= 1) {   // merge across the 4 quads
            float c1 = __shfl_xor(a1, o, 64);
            int   j1 = __shfl_xor(x1, o, 64);
            float c2 = __shfl_xor(a2, o, 64);
            int   j2 = __shfl_xor(x2, o, 64);
            if (c1 > a1) {
                a2 = fmaxf(a1, c2); x2 = (a1 >= c2) ? x1 : j2;
                a1 = c1; x1 = j1;
            } else {
                x2 = (a2 >= c1) ? x2 : j1;
                a2 = fmaxf(a2, c1);
            }
        }
        if (quad == 0) {
            int row = row0 + wn * 64 + nj * 16 + l15;
            size_t b = (size_t)row * CPR + (ct * 4 + wm * 2);
            cand_s[b]     = a1;  cand_i[b]     = x1;
            cand_s[b + 1] = a2;  cand_i[b + 1] = x2;
        }
    }
}

// --------- kernel 2: exact fp32 rescore of surviving CODES + gather ---------
__global__ __launch_bounds__(256) void rescore_kernel(
    const float* __restrict__ x, const float* __restrict__ embed,
    const float* __restrict__ e_sq, const float* __restrict__ f_sq,
    const float* __restrict__ cand_s, const int* __restrict__ cand_i,
    float* __restrict__ out)
{
    int row = blockIdx.x * 4 + (threadIdx.x >> 6);
    int lane = threadIdx.x & 63;
    size_t cb = (size_t)row * CPR;

    float cs0 = cand_s[cb + lane];
    float cs1 = cand_s[cb + 64 + lane];
    int   ci0 = cand_i[cb + lane];
    int   ci1 = cand_i[cb + 64 + lane];

    float m = fmaxf(cs0, cs1);
    #pragma unroll
    for (int o = 32; o >= 1; o >>= 1) m = fmaxf(m, __shfl_xor(m, o, 64));

    unsigned long long mask0 = __ballot(cs0 >= m - MARGIN);
    unsigned long long mask1 = __ballot(cs1 >= m - MARGIN);

    const float4* xsrc = (const float4*)(x + (size_t)row * DIM + lane * 8);
    float4 xa = xsrc[0], xb = xsrc[1];
    float fsq = f_sq[row];

    float bd = NEG_INF;
    int   bi = 0x7fffffff;

    #pragma unroll
    for (int s = 0; s < 2; ++s) {
        unsigned long long mask = s ? mask1 : mask0;
        while (mask) {
            int p = __ffsll(mask) - 1;
            mask &= mask - 1;
            int c = __shfl(s ? ci1 : ci0, p);
            const float4* er = (const float4*)(embed + (size_t)c * DIM + lane * 8);
            float4 ea = er[0], eb = er[1];
            float part = xa.x*ea.x + xa.y*ea.y + xa.z*ea.z + xa.w*ea.w
                       + xb.x*eb.x + xb.y*eb.y + xb.z*eb.z + xb.w*eb.w;
            #pragma unroll
            for (int o = 32; o >= 1; o >>= 1) part += __shfl_xor(part, o, 64);
            float d = -((fsq - 2.0f * part) + e_sq[c]);   // np rounding order
            if (d > bd || (d == bd && c < bi)) { bd = d; bi = c; }
        }
    }

    const float4* er = (const float4*)(embed + (size_t)bi * DIM + lane * 8);
    float4 qa = er[0], qb = er[1];
    float4* dst = (float4*)(out + (size_t)row * DIM + lane * 8);
    dst[0] = qa; dst[1] = qb;
    if (lane == 0) out[(size_t)NROWS * DIM + row] = (float)bi;
}

extern "C" void kernel_launch(void* const* d_in, const int* in_sizes, int n_in,
                              void* d_out, int out_size, void* d_ws, size_t ws_size,
                              hipStream_t stream)
{
    const float* x     = (const float*)d_in[0];   // [16384, 512] fp32
    const float* embed = (const float*)d_in[1];   // [8192, 512] fp32
    float* out = (float*)d_out;

    // ws layout (~21 MB), all 16B-aligned
    float* e_sq    = (float*)d_ws;                              // 8192
    float* esqh    = e_sq + KCODES;                             // 8192 (-e_sq/2)
    float* f_sq    = esqh + KCODES;                             // 16384
    float* e_scale = f_sq + NROWS;                              // 8192
    float* f_scale = e_scale + KCODES;                          // 16384
    float* cand_s  = f_scale + NROWS;                           // 16384*128
    int*   cand_i  = (int*)(cand_s + (size_t)NROWS * CPR);      // 16384*128
    int4*  e_t8    = (int4*)(cand_i + (size_t)NROWS * CPR);     // [32][8192] int4 = 4 MB

    // x_t8 lives in d_out scratch (8 MB of 33.6 MB); rescore overwrites later.
    int4* x_t8 = (int4*)d_out;

    (void)in_sizes; (void)n_in; (void)out_size; (void)ws_size;

    convert_kernel<<<(KCODES + NROWS) / 32, 512, 0, stream>>>(
        x, embed, e_t8, x_t8, e_sq, esqh, f_sq, e_scale, f_scale);
    screen_kernel<<<2048, 512, 0, stream>>>(
        e_t8, x_t8, esqh, e_scale, f_scale, cand_s, cand_i);
    rescore_kernel<<<NROWS / 4, 256, 0, stream>>>(
        x, embed, e_sq, f_sq, cand_s, cand_i, out);
}